// Round 6
// baseline (1084.404 us; speedup 1.0000x reference)
//
#include <hip/hip_runtime.h>

#define NNODES 2000
#define BATCH  64
#define DIM    256
#define GRID   256
#define BLOCK  256

typedef __attribute__((ext_vector_type(8))) short  v8s;
typedef __attribute__((ext_vector_type(8))) __bf16 v8bf;
typedef __attribute__((ext_vector_type(4))) float  v4f;
typedef __attribute__((ext_vector_type(4))) int    v4i;

__device__ __forceinline__ short f2bf(float f) {
  unsigned u = __builtin_bit_cast(unsigned, f);
  u += 0x7FFFu + ((u >> 16) & 1u);            // RNE
  return (short)(u >> 16);
}
__device__ __forceinline__ float bf2f(short s) {
  unsigned u = ((unsigned)(unsigned short)s) << 16;
  return __builtin_bit_cast(float, u);
}
__device__ __forceinline__ v4f mfma16(v8s a, v8s b, v4f c) {
  return __builtin_amdgcn_mfma_f32_16x16x32_bf16(
      __builtin_bit_cast(v8bf, a), __builtin_bit_cast(v8bf, b), c, 0, 0, 0);
}
__device__ __forceinline__ float sigmoidf(float x) {
  return __builtin_amdgcn_rcpf(1.0f + __builtin_amdgcn_exp2f(-1.4426950408889634f * x));
}

// prep0: weight transforms + scheduler-state init.
// Wt_in[j][k] = bf16(W_in[k][j]); Wt_inner[j][k] = bf16(W0[k][j]+W1[k][j] | W2[k][j])
// (folds h=[mean,mean,min]: mean@(W0+W1) + min@W2). queue[i]=-1, pending[i]=#children,
// parent[c]=i (every node 1..N-1 is exactly one node's child; node 0 never read), head=tail=0.
__global__ void prep_kernel(const float* __restrict__ W_in, const float* __restrict__ W_inner,
                            const int* __restrict__ structure,
                            short* __restrict__ Wt_in, short* __restrict__ Wt_inner,
                            int* __restrict__ queue, int* __restrict__ pending,
                            int* __restrict__ parent, int* __restrict__ qhead,
                            int* __restrict__ qtail) {
  int idx = blockIdx.x * blockDim.x + threadIdx.x;
  int stride = gridDim.x * blockDim.x;
  for (int i = idx; i < 256 * 256; i += stride) {
    int j = i >> 8, k = i & 255;
    Wt_in[j * 256 + k] = f2bf(W_in[k * 256 + j]);
  }
  for (int i = idx; i < 256 * 512; i += stride) {
    int j = i >> 9, k = i & 511;
    float v = W_inner[(k + 256) * 256 + j];
    if (k < 256) v += W_inner[k * 256 + j];
    Wt_inner[j * 512 + k] = f2bf(v);
  }
  for (int i = idx; i < NNODES; i += stride) {
    queue[i] = -1;
    const int s = structure[2 * i];
    const int e = structure[2 * i + 1];
    pending[i] = (s < 0) ? 0 : (e - s);
    if (s >= 0)
      for (int c = s; c < e; ++c) parent[c] = i;   // disjoint ranges: race-free
  }
  if (idx == 0) { *qhead = 0; *qtail = 0; }
}

// prep1: seed the ready-queue with all leaves (runs after prep0; stream-ordered).
__global__ void seed_kernel(const int* __restrict__ structure, int* __restrict__ queue,
                            int* __restrict__ qtail) {
  int idx = blockIdx.x * blockDim.x + threadIdx.x;
  int stride = gridDim.x * blockDim.x;
  for (int i = idx; i < NNODES; i += stride) {
    if (structure[2 * i] < 0) {
      int slot = atomicAdd(qtail, 1);
      atomicExch(&queue[slot], i);
    }
  }
}

// Dataflow tree evaluation with a device-side ready-queue (dynamic scheduling).
// Blocks pop slots via atomicAdd(head) and spin only on their own slot; every node is
// pushed exactly once when its last child completes, so all slots < NNODES fill =>
// progress => deadlock-free under cooperative co-residency (GRID=256, proven geometry).
// Node body is the R5-proven one: barrier-free MFMA K-loop (A from padded LDS,
// B straight from transposed W in global/L2), two M=32 halves.
__launch_bounds__(BLOCK, 1)
__global__ void tree_kernel(const int* __restrict__ structure, const float* __restrict__ features,
                            const float* __restrict__ b_in, const float* __restrict__ b_inner,
                            const short* __restrict__ Wt_in, const short* __restrict__ Wt_inner,
                            short* __restrict__ state, int* queue, int* pending,
                            const int* __restrict__ parent, int* qhead, int* qtail,
                            float* __restrict__ out) {
  __shared__ short Xs[32][520];   // 32 batch rows x K(<=512), pad->520 (proven layout)
  __shared__ int s_node;

  const int tid  = threadIdx.x;
  const int wave = tid >> 6;
  const int lane = tid & 63;
  const int ln15 = lane & 15;
  const int quad = lane >> 4;

  for (;;) {
    // ---- pop next ready node (thread 0), broadcast via LDS ----
    if (tid == 0) {
      int my = atomicAdd(qhead, 1);
      int n = -1;
      if (my < NNODES) {
        int guard = 0;
        while ((n = atomicAdd(&queue[my], 0)) < 0 && guard < (1 << 22)) {
          __builtin_amdgcn_s_sleep(2); ++guard;
        }
      }
      s_node = n;
    }
    __syncthreads();
    const int node = s_node;
    if (node < 0) break;
    __threadfence();   // acquire: children's state stores visible (L1 inv, cross-XCD)

    const int s = structure[2 * node];
    const int e = structure[2 * node + 1];
    const bool leaf = (s < 0);
    const int K = leaf ? 256 : 512;
    const short* __restrict__ W = leaf ? Wt_in : Wt_inner;
    const float* __restrict__ bias = leaf ? b_in : b_inner;

    for (int half = 0; half < 2; ++half) {
      __syncthreads();   // prior consumers of Xs are done

      // ---- build Xs (bf16) for batches [half*32, half*32+32) ----
      {
        const int bl = tid >> 3;            // 0..31
        const int b  = half * 32 + bl;
        const int d0 = (tid & 7) * 32;
        const float* __restrict__ fp = features + ((size_t)b * NNODES + node) * DIM;
        if (leaf) {
          #pragma unroll
          for (int d = 0; d < 32; d += 4) {
            const float4 f = *(const float4*)(fp + d0 + d);
            short4 o; o.x = f2bf(f.x); o.y = f2bf(f.y); o.z = f2bf(f.z); o.w = f2bf(f.w);
            *(short4*)&Xs[bl][d0 + d] = o;
          }
        } else {
          const float inv = 1.0f / (float)(e - s + 1);
          #pragma unroll
          for (int d = 0; d < 32; d += 4) {
            const float4 f = *(const float4*)(fp + d0 + d);
            float sm0 = f.x, sm1 = f.y, sm2 = f.z, sm3 = f.w;
            float mn0 = f.x, mn1 = f.y, mn2 = f.z, mn3 = f.w;
            for (int c = s; c < e; ++c) {
              const short4 cv = *(const short4*)(state + ((size_t)c * BATCH + b) * DIM + d0 + d);
              float v0 = bf2f(cv.x), v1 = bf2f(cv.y), v2 = bf2f(cv.z), v3 = bf2f(cv.w);
              sm0 += v0; sm1 += v1; sm2 += v2; sm3 += v3;
              mn0 = fminf(mn0, v0); mn1 = fminf(mn1, v1); mn2 = fminf(mn2, v2); mn3 = fminf(mn3, v3);
            }
            short4 om; om.x = f2bf(sm0 * inv); om.y = f2bf(sm1 * inv); om.z = f2bf(sm2 * inv); om.w = f2bf(sm3 * inv);
            *(short4*)&Xs[bl][d0 + d] = om;                 // c_mean -> k in [0,256)
            short4 on; on.x = f2bf(mn0); on.y = f2bf(mn1); on.z = f2bf(mn2); on.w = f2bf(mn3);
            *(short4*)&Xs[bl][256 + d0 + d] = on;           // c_min  -> k in [256,512)
          }
        }
      }
      __syncthreads();

      // ---- GEMM: [32 x K] @ Wt^T -> [32 x 256], barrier-free K loop ----
      v4f acc[2][4];
      #pragma unroll
      for (int mt = 0; mt < 2; ++mt)
        #pragma unroll
        for (int nt = 0; nt < 4; ++nt) acc[mt][nt] = v4f{0.0f, 0.0f, 0.0f, 0.0f};

      const int nkc = K >> 5;
      for (int kc = 0; kc < nkc; ++kc) {
        v8s af[2], bfr[4];
        #pragma unroll
        for (int nt = 0; nt < 4; ++nt)
          bfr[nt] = *(const v8s*)(W + (size_t)(wave * 64 + nt * 16 + ln15) * K + kc * 32 + quad * 8);
        #pragma unroll
        for (int mt = 0; mt < 2; ++mt)
          af[mt] = *(const v8s*)&Xs[mt * 16 + ln15][kc * 32 + quad * 8];
        #pragma unroll
        for (int mt = 0; mt < 2; ++mt)
          #pragma unroll
          for (int nt = 0; nt < 4; ++nt)
            acc[mt][nt] = mfma16(af[mt], bfr[nt], acc[mt][nt]);
      }

      // ---- epilogue: bias + sigmoid, store state (bf16) and root output (fp32) ----
      #pragma unroll
      for (int mt = 0; mt < 2; ++mt) {
        #pragma unroll
        for (int nt = 0; nt < 4; ++nt) {
          const int j = wave * 64 + nt * 16 + ln15;
          const float bs = bias[j];
          #pragma unroll
          for (int r = 0; r < 4; ++r) {
            const int bb = half * 32 + mt * 16 + quad * 4 + r;
            const float v = sigmoidf(acc[mt][nt][r] + bs);
            state[((size_t)node * BATCH + bb) * DIM + j] = f2bf(v);
            if (node == 0) out[bb * DIM + j] = v;
          }
        }
      }
    } // half

    __threadfence();      // release: state stores device-visible
    __syncthreads();
    if (tid == 0 && node != 0) {
      const int p = parent[node];
      if (atomicSub(&pending[p], 1) == 1) {       // last child done -> parent ready
        int slot = atomicAdd(qtail, 1);
        atomicExch(&queue[slot], p);
      }
    }
  }
}

extern "C" void kernel_launch(void* const* d_in, const int* in_sizes, int n_in,
                              void* d_out, int out_size, void* d_ws, size_t ws_size,
                              hipStream_t stream) {
  const int*   structure = (const int*)d_in[0];
  const float* features  = (const float*)d_in[1];
  const float* W_in      = (const float*)d_in[2];
  const float* b_in      = (const float*)d_in[3];
  const float* W_inner   = (const float*)d_in[4];
  const float* b_inner   = (const float*)d_in[5];
  float* out = (float*)d_out;

  char* ws = (char*)d_ws;
  short* state = (short*)ws;                                   // 2000*64*256*2 = 65,536,000 B
  size_t off = (size_t)NNODES * BATCH * DIM * 2;
  short* Wt_in = (short*)(ws + off);    off += 256 * 256 * 2;  // 131,072 B
  short* Wt_inner = (short*)(ws + off); off += 512 * 256 * 2;  // 262,144 B
  int* queue   = (int*)(ws + off);      off += NNODES * 4;
  int* pending = (int*)(ws + off);      off += NNODES * 4;
  int* parent  = (int*)(ws + off);      off += NNODES * 4;
  int* qhead   = (int*)(ws + off);      off += 4;
  int* qtail   = (int*)(ws + off);      off += 4;

  prep_kernel<<<dim3(256), dim3(256), 0, stream>>>(W_in, W_inner, structure,
                                                   Wt_in, Wt_inner, queue, pending,
                                                   parent, qhead, qtail);
  seed_kernel<<<dim3(32), dim3(256), 0, stream>>>(structure, queue, qtail);

  void* args[13];
  args[0]  = (void*)&structure;
  args[1]  = (void*)&features;
  args[2]  = (void*)&b_in;
  args[3]  = (void*)&b_inner;
  args[4]  = (void*)&Wt_in;
  args[5]  = (void*)&Wt_inner;
  args[6]  = (void*)&state;
  args[7]  = (void*)&queue;
  args[8]  = (void*)&pending;
  args[9]  = (void*)&parent;
  args[10] = (void*)&qhead;
  args[11] = (void*)&qtail;
  args[12] = (void*)&out;
  hipLaunchCooperativeKernel((void*)tree_kernel, dim3(GRID), dim3(BLOCK), args, 0, stream);
}